// Round 1
// baseline (444.990 us; speedup 1.0000x reference)
//
#include <hip/hip_runtime.h>

// LIF neuron scan: x [B,T,N] fp32 -> spikes [B,T,N] fp32
//   mem = 0.25*mem + x_t ; spike = mem > 1.0 ; mem = spike ? 0 : mem
//
// R3 change (two levers, both aimed at the ~12 us gap between the kernel's
// ~97 us and the 85 us copy-roofline):
//  1. float4 chains (4 consecutive n per thread). Wave transaction becomes
//     1 KiB contiguous (matches the 6.29 TB/s copy ubench) and resident
//     stream count drops 4x (512 blocks vs 2048) -> better HBM row locality.
//  2. Stores are now REGULAR (cached) instead of nontemporal. vmcnt retires
//     in issue order, so consuming the load issued DEPTH iters back also
//     waits on every store interleaved before it; nt stores retire at HBM
//     latency, regular stores retire on L2 accept. Loads stay nontemporal so
//     the read-once input doesn't pollute L2 and the full 32 MiB is left for
//     write coalescing (the 6.55 TB/s fills use cached stores).
// Occupancy drops to 2 blocks/CU (8 waves/CU) but Little's law needs only
// ~2.3 KiB/SIMD in flight and the depth-8 float4 ring holds 16 KiB/SIMD.

typedef float f4 __attribute__((ext_vector_type(4)));

static constexpr int   T_STEPS = 128;
static constexpr int   N_FEAT  = 8192;          // 2^13
static constexpr int   NV      = N_FEAT / 4;    // 2048 float4 per [b,t] row
static constexpr int   DEPTH   = 8;             // prefetch distance (ring)
static constexpr float TAU     = 0.25f;
static constexpr float V_TH    = 1.0f;

__global__ __launch_bounds__(256) void lif_scan_kernel(
    const f4* __restrict__ x, f4* __restrict__ out, int n_vchains) {
    int tid = blockIdx.x * blockDim.x + threadIdx.x;  // 0 .. B*NV-1
    if (tid >= n_vchains) return;

    int b = tid >> 11;            // tid / NV
    int n = tid & (NV - 1);       // tid % NV
    // float4 index of [b, t, n4] is (b*T + t)*NV + n4
    const size_t base = (size_t)b * T_STEPS * NV + n;

    f4 buf[DEPTH];
    // Prime the pipeline: DEPTH independent 16B loads back-to-back.
#pragma unroll
    for (int d = 0; d < DEPTH; ++d)
        buf[d] = __builtin_nontemporal_load(&x[base + (size_t)d * NV]);

    f4 mem = (f4)0.f;
    // Full unroll: t & (DEPTH-1) is compile-time, buf[] stays in registers,
    // each consume waits only on its own load (vmcnt(DEPTH-ish)).
#pragma unroll
    for (int t = 0; t < T_STEPS; ++t) {
        f4 xt = buf[t & (DEPTH - 1)];
        if (t + DEPTH < T_STEPS)
            buf[t & (DEPTH - 1)] =
                __builtin_nontemporal_load(&x[base + (size_t)(t + DEPTH) * NV]);
        f4 s;
#pragma unroll
        for (int j = 0; j < 4; ++j) {
            // 0.25*mem is exact (pow2 scale) -> bitwise matches the reference
            float m = TAU * mem[j] + xt[j];
            const bool sp = m > V_TH;
            s[j]   = sp ? 1.f : 0.f;
            mem[j] = sp ? 0.f : m;
        }
        out[base + (size_t)t * NV] = s;   // cached store: retires on L2 accept
    }
}

extern "C" void kernel_launch(void* const* d_in, const int* in_sizes, int n_in,
                              void* d_out, int out_size, void* d_ws, size_t ws_size,
                              hipStream_t stream) {
    const f4* x   = (const f4*)d_in[0];
    f4*       out = (f4*)d_out;

    int total     = in_sizes[0];               // B*T*N
    int n_vchains = total / T_STEPS / 4;       // B*N/4 = 131072
    int block     = 256;
    int grid      = (n_vchains + block - 1) / block;  // 512

    lif_scan_kernel<<<grid, block, 0, stream>>>(x, out, n_vchains);
}

// Round 2
// 432.044 us; speedup vs baseline: 1.0300x; 1.0300x over previous
//
#include <hip/hip_runtime.h>

// LIF neuron scan: x [B,T,N] fp32 -> spikes [B,T,N] fp32
//   mem = 0.25*mem + x_t ; spike = mem > 1.0 ; mem = spike ? 0 : mem
//
// R4: revert R3's float4 (2 waves/SIMD killed the TLP that was hiding the
// consume-side vmcnt drains: kernel 95 -> 115 us). Back to the scalar
// 8-waves/SIMD depth-8 register ring, with ONE isolated change vs R2:
// stores are regular cached stores, not nontemporal. vmcnt retires in issue
// order, so consuming buf[t&7] also waits on every store issued before that
// load; cached stores retire on L2-accept (~200 cyc) while nt (stream
// policy) stores retire near HBM latency. Loads stay nontemporal: the input
// is read-once and shouldn't pollute L2, which the write stream can use.
//
// Occupancy: 524288 threads / 64 = 8192 waves = 8 waves/SIMD (full for this
// VGPR count). In-flight: 8 waves x 256 B x 8 deep = 16 KiB/SIMD vs ~2.3 KiB
// Little's-law requirement at 6.3 TB/s & ~900 cyc latency.

static constexpr int   T_STEPS = 128;
static constexpr int   N_FEAT  = 8192;   // 2^13
static constexpr int   DEPTH   = 8;      // prefetch distance
static constexpr float TAU     = 0.25f;
static constexpr float V_TH    = 1.0f;

__global__ __launch_bounds__(256) void lif_scan_kernel(
    const float* __restrict__ x, float* __restrict__ out, int n_chains) {
    int tid = blockIdx.x * blockDim.x + threadIdx.x;  // 0 .. B*N-1
    if (tid >= n_chains) return;

    int b = tid >> 13;            // tid / N_FEAT
    int n = tid & (N_FEAT - 1);   // tid % N_FEAT
    // element index of [b, t, n] is (b*T + t)*N + n
    const size_t base = (size_t)b * T_STEPS * N_FEAT + n;

    float buf[DEPTH];
    // Prime the pipeline: DEPTH independent loads issued back-to-back.
#pragma unroll
    for (int d = 0; d < DEPTH; ++d)
        buf[d] = __builtin_nontemporal_load(&x[base + (size_t)d * N_FEAT]);

    float mem = 0.f;
    // Full unroll: t & (DEPTH-1) is compile-time, buf[] stays in registers,
    // each consume waits only on its own load (plus older stores).
#pragma unroll
    for (int t = 0; t < T_STEPS; ++t) {
        float xt = buf[t & (DEPTH - 1)];
        if (t + DEPTH < T_STEPS)
            buf[t & (DEPTH - 1)] =
                __builtin_nontemporal_load(&x[base + (size_t)(t + DEPTH) * N_FEAT]);
        // 0.25*mem is exact (pow2 scale) -> bitwise matches numpy reference
        mem = TAU * mem + xt;
        float s = (mem > V_TH) ? 1.f : 0.f;
        mem     = (mem > V_TH) ? 0.f : mem;
        out[base + (size_t)t * N_FEAT] = s;   // cached store: retires on L2 accept
    }
}

extern "C" void kernel_launch(void* const* d_in, const int* in_sizes, int n_in,
                              void* d_out, int out_size, void* d_ws, size_t ws_size,
                              hipStream_t stream) {
    const float* x   = (const float*)d_in[0];
    float*       out = (float*)d_out;

    int total    = in_sizes[0];          // B*T*N
    int n_chains = total / T_STEPS;      // B*N
    int block    = 256;
    int grid     = (n_chains + block - 1) / block;

    lif_scan_kernel<<<grid, block, 0, stream>>>(x, out, n_chains);
}

// Round 3
// 427.964 us; speedup vs baseline: 1.0398x; 1.0095x over previous
//
#include <hip/hip_runtime.h>

// LIF neuron scan: x [B,T,N] fp32 -> spikes [B,T,N] fp32
//   mem = 0.25*mem + x_t ; spike = mem > 1.0 ; mem = spike ? 0 : mem
//
// R5: restore the session-best configuration (R2) exactly. The two levers
// tried since both regressed:
//   - R3 float4: 2 waves/SIMD killed TLP-based latency hiding (kernel
//     95 -> 115 us). Scalar/8-waves-per-SIMD is the right point: wave
//     switching, not ring depth, hides the consume-side drains.
//   - R4 cached stores: kernel ~97 -> ~104 us. Store vmcnt retires on
//     VGPR-read, not DRAM-commit, so nt stores never cost drain latency;
//     nt avoids L2 write-allocate churn against the nt load stream.
// Kernel runs ~97 us = 5.65 TB/s on 537 MB minimal traffic, 90% of the
// 6.29 TB/s measured copy ceiling for mixed read+write streams. Total
// bench = 2x ~164 us harness fills + kernel ~= 425 us vs 413 us ideal.
// This is the streaming-memory roofline.

static constexpr int   T_STEPS = 128;
static constexpr int   N_FEAT  = 8192;   // 2^13
static constexpr int   DEPTH   = 8;      // prefetch distance
static constexpr float TAU     = 0.25f;
static constexpr float V_TH    = 1.0f;

__global__ __launch_bounds__(256) void lif_scan_kernel(
    const float* __restrict__ x, float* __restrict__ out, int n_chains) {
    int tid = blockIdx.x * blockDim.x + threadIdx.x;  // 0 .. B*N-1
    if (tid >= n_chains) return;

    int b = tid >> 13;            // tid / N_FEAT
    int n = tid & (N_FEAT - 1);   // tid % N_FEAT
    // element index of [b, t, n] is (b*T + t)*N + n
    const size_t base = (size_t)b * T_STEPS * N_FEAT + n;

    float buf[DEPTH];
    // Prime the pipeline: DEPTH independent loads issued back-to-back.
#pragma unroll
    for (int d = 0; d < DEPTH; ++d)
        buf[d] = __builtin_nontemporal_load(&x[base + (size_t)d * N_FEAT]);

    float mem = 0.f;
    // Full unroll: t & (DEPTH-1) is compile-time, buf[] stays in registers,
    // each consume waits only on its own load.
#pragma unroll
    for (int t = 0; t < T_STEPS; ++t) {
        float xt = buf[t & (DEPTH - 1)];
        if (t + DEPTH < T_STEPS)
            buf[t & (DEPTH - 1)] =
                __builtin_nontemporal_load(&x[base + (size_t)(t + DEPTH) * N_FEAT]);
        // 0.25*mem is exact (pow2 scale) -> bitwise matches numpy reference
        mem = TAU * mem + xt;
        float s = (mem > V_TH) ? 1.f : 0.f;
        mem     = (mem > V_TH) ? 0.f : mem;
        __builtin_nontemporal_store(s, &out[base + (size_t)t * N_FEAT]);
    }
}

extern "C" void kernel_launch(void* const* d_in, const int* in_sizes, int n_in,
                              void* d_out, int out_size, void* d_ws, size_t ws_size,
                              hipStream_t stream) {
    const float* x   = (const float*)d_in[0];
    float*       out = (float*)d_out;

    int total    = in_sizes[0];          // B*T*N
    int n_chains = total / T_STEPS;      // B*N
    int block    = 256;
    int grid     = (n_chains + block - 1) / block;

    lif_scan_kernel<<<grid, block, 0, stream>>>(x, out, n_chains);
}